// Round 9
// baseline (572.251 us; speedup 1.0000x reference)
//
#include <hip/hip_runtime.h>

#define NN 50000
#define NE 800000
#define DD 128

#define NBUCK 196   // ceil(NN/256), bucket = dst >> 8
#define EPB   2048  // edges per block in pass 1
#define B1    391   // ceil(NE/EPB)
#define CAP   5120  // max edges per bucket (mean 4082, std 64 -> +16 sigma)
#define CONVB 12500 // NN/4 conv blocks
#define PREPB 128   // 2*128*256/512
#define NHALF 25000 // nodes per half (partition axis 2)
#define GRP   391   // ceil(NHALF/64) 64-node groups per partition
#define AGGBLK 2048 // persistent blocks for agg

typedef __attribute__((ext_vector_type(8))) short short8v;
typedef __attribute__((ext_vector_type(4))) float float4v;

static __device__ __forceinline__ unsigned short f2b(float f) {
  union { float f; unsigned u; } v; v.f = f;
  unsigned r = v.u + 0x7fff + ((v.u >> 16) & 1);
  return (unsigned short)(r >> 16);
}
static __device__ __forceinline__ float b2f(unsigned short b) {
  union { unsigned u; float f; } v; v.u = ((unsigned)b) << 16;
  return v.f;
}

// exclusive scan over 256 threads (trailing barrier makes ws reusable)
static __device__ __forceinline__ int excl_scan256(int v, int* ws) {
  int t = threadIdx.x, lane = t & 63, w = t >> 6;
  int s = v;
  #pragma unroll
  for (int off = 1; off < 64; off <<= 1) {
    int u = __shfl_up(s, off);
    if (lane >= off) s += u;
  }
  if (lane == 63) ws[w] = s;
  __syncthreads();
  int add = 0;
  #pragma unroll
  for (int k = 0; k < 3; ++k)
    if (k < w) add += ws[k];
  __syncthreads();
  return add + s - v;
}

// ---- k_prep: role-split {histogram | x->bf16 + x.Ws | weight pack} ----

__global__ __launch_bounds__(256) void k_prep(
    const int* __restrict__ dst, int* __restrict__ ghist,
    const float* __restrict__ x, const float* __restrict__ Wsc,
    unsigned short* __restrict__ xb, float* __restrict__ xw,
    const float* __restrict__ Wl1, const float* __restrict__ Wr1,
    const float* __restrict__ Wl2, const float* __restrict__ Wr2,
    unsigned short* __restrict__ W1, unsigned short* __restrict__ W2) {
  __shared__ int hs[NBUCK];
  const int b = blockIdx.x;
  const int t = threadIdx.x;
  if (b < B1) {
    for (int i = t; i < NBUCK; i += 256) hs[i] = 0;
    __syncthreads();
    int base = b * EPB;
    for (int i = t; i < EPB; i += 256) {
      int e = base + i;
      if (e < NE) atomicAdd(&hs[dst[e] >> 8], 1);
    }
    __syncthreads();
    for (int i = t; i < NBUCK; i += 256) ghist[b * NBUCK + i] = hs[i];
  } else if (b < B1 + CONVB) {
    int node = (b - B1) * 4 + (t >> 6);
    int lane = t & 63;
    float2 v = *(const float2*)(x + (size_t)node * DD + lane * 2);
    ushort2 o; o.x = f2b(v.x); o.y = f2b(v.y);
    *(ushort2*)(xb + (size_t)node * DD + lane * 2) = o;
    float p = v.x * Wsc[lane * 2] + v.y * Wsc[lane * 2 + 1];
    #pragma unroll
    for (int m = 1; m < 64; m <<= 1) p += __shfl_xor(p, m);
    if (lane == 0) xw[node] = p;
  } else {
    int idx0 = ((b - B1 - CONVB) * 256 + t) * 2;
    #pragma unroll
    for (int u = 0; u < 2; ++u) {
      int idx = idx0 + u;
      int half = idx >> 15;
      int i = idx & 32767;
      int o = i >> 8;
      int k = i & 255;
      const float* Wl = half ? Wl2 : Wl1;
      const float* Wr = half ? Wr2 : Wr1;
      float v = (k < DD) ? Wl[o * DD + k] : Wr[o * DD + (k - DD)];
      (half ? W2 : W1)[i] = f2b(v);
    }
  }
}

// ---- scan_cols: one block per bucket, scan 391 per-block counts ----

__global__ __launch_bounds__(256) void scan_cols(const int* __restrict__ ghist,
                                                 int* __restrict__ goff,
                                                 int* __restrict__ btot) {
  __shared__ int ws[4];
  const int j = blockIdx.x, t = threadIdx.x;
  int b0 = 2 * t, b1 = 2 * t + 1;
  int v0 = (b0 < B1) ? ghist[b0 * NBUCK + j] : 0;
  int v1 = (b1 < B1) ? ghist[b1 * NBUCK + j] : 0;
  int excl = excl_scan256(v0 + v1, ws);
  if (b0 < B1) goff[b0 * NBUCK + j] = excl;
  if (b1 < B1) goff[b1 * NBUCK + j] = excl + v0;
  if (t == 255) btot[j] = excl + v0 + v1;
}

// ---- scatter1: in-block binstart scan + bucket scatter ----

__global__ __launch_bounds__(256) void scatter1(const int* __restrict__ src,
                                                const int* __restrict__ dst,
                                                const int* __restrict__ goff,
                                                const int* __restrict__ btot,
                                                unsigned* __restrict__ tmp) {
  __shared__ int cur[NBUCK];
  __shared__ int ws[4];
  const int t = threadIdx.x;
  int vb = (t < NBUCK) ? btot[t] : 0;
  int exb = excl_scan256(vb, ws);
  if (t < NBUCK) cur[t] = exb + goff[blockIdx.x * NBUCK + t];
  __syncthreads();
  int base = blockIdx.x * EPB;
  for (int i = t; i < EPB; i += 256) {
    int e = base + i;
    if (e < NE) {
      int d = dst[e];
      int pos = atomicAdd(&cur[d >> 8], 1);
      tmp[pos] = ((unsigned)(d & 255) << 20) | (unsigned)src[e];
    }
  }
}

// ---- bucketsort: one block per bucket, LDS counting sort -> rowptr/col ----

__global__ __launch_bounds__(256) void bucketsort(const unsigned* __restrict__ tmp,
                                                  const int* __restrict__ btot,
                                                  int* __restrict__ rowptr,
                                                  int* __restrict__ col) {
  __shared__ unsigned vals[CAP];
  __shared__ int cnt[256];
  __shared__ int ws[4];
  __shared__ int s0_sh;
  const int b = blockIdx.x, j = threadIdx.x;
  int vb = (j < NBUCK) ? btot[j] : 0;
  int exb = excl_scan256(vb, ws);
  if (j == b) s0_sh = exb;
  cnt[j] = 0;
  __syncthreads();
  const int s0 = s0_sh;
  int n = btot[b];
  if (n > CAP) n = CAP;
  for (int i = j; i < n; i += 256) {
    unsigned v = tmp[s0 + i];
    vals[i] = v;
    atomicAdd(&cnt[v >> 20], 1);
  }
  __syncthreads();
  int c = cnt[j];
  int excl = excl_scan256(c, ws);
  int node = b * 256 + j;
  if (node < NN) rowptr[node] = s0 + excl;
  if (b == 0 && j == 0) rowptr[NN] = NE;
  cnt[j] = excl;  // reuse as cursor (scan helper ended with a barrier)
  __syncthreads();
  for (int i = j; i < n; i += 256) {
    unsigned v = vals[i];
    int pos = atomicAdd(&cnt[v >> 20], 1);
    col[s0 + pos] = (int)(v & 0xFFFFF);
  }
}

// ---- agg_queue: XCD-exact stripe gather via HW_REG_XCC_ID work queues ----
// Partition p = stripe(p&3) x half(p>>2); each partition's gather footprint is
// a 3.2MB column stripe -> fits one XCD's private 4MB L2. Persistent blocks
// read their REAL XCD id and drain their own partition's ticket queue first,
// then steal (correct under any dispatch mapping). col/rowptr/aggs accesses
// are nontemporal so streams don't evict the stripe.

__global__ __launch_bounds__(256) void agg_queue(const unsigned short* __restrict__ h,
                                                 const int* __restrict__ rowptr,
                                                 const int* __restrict__ col,
                                                 int* __restrict__ ctr,
                                                 unsigned short* __restrict__ aggs) {
  __shared__ int gsh;
  const int t = threadIdx.x;
  int xcd;
  asm volatile("s_getreg_b32 %0, hwreg(HW_REG_XCC_ID)" : "=s"(xcd));
  xcd &= 7;
  const int q = t & 3;
  for (int p = 0; p < 8; ++p) {
    const int part = (xcd + p) & 7;
    const int stripe = part & 3;
    const int half = part >> 2;
    const int limit = half ? NN : NHALF;
    const unsigned short* hb = h + stripe * 32 + q * 8;
    while (true) {
      __syncthreads();
      if (t == 0) gsh = atomicAdd(&ctr[part], 1);
      __syncthreads();
      int g = gsh;
      if (g >= GRP) break;
      int node = half * NHALF + g * 64 + (t >> 2);
      if (node < limit) {
        int beg = __builtin_nontemporal_load(rowptr + node);
        int end = __builtin_nontemporal_load(rowptr + node + 1);
        float acc[8] = {0.f, 0.f, 0.f, 0.f, 0.f, 0.f, 0.f, 0.f};
        int e = beg;
        for (; e + 8 <= end; e += 8) {
          short8v v[8];
          #pragma unroll
          for (int j = 0; j < 8; ++j) {
            int s = __builtin_nontemporal_load(col + e + j);
            v[j] = *(const short8v*)(hb + (size_t)s * DD);
          }
          #pragma unroll
          for (int j = 0; j < 8; ++j)
            #pragma unroll
            for (int k = 0; k < 8; ++k) acc[k] += b2f((unsigned short)v[j][k]);
        }
        for (; e < end; ++e) {
          int s = __builtin_nontemporal_load(col + e);
          short8v v = *(const short8v*)(hb + (size_t)s * DD);
          #pragma unroll
          for (int k = 0; k < 8; ++k) acc[k] += b2f((unsigned short)v[k]);
        }
        float inv = 1.0f / fmaxf((float)(end - beg), 1.0f);
        short8v o;
        #pragma unroll
        for (int k = 0; k < 8; ++k) o[k] = (short)f2b(acc[k] * inv);
        __builtin_nontemporal_store(o, (short8v*)(aggs + ((size_t)stripe * NN + node) * 32 + q * 8));
      }
    }
  }
}

// ---------------- fused MFMA linear layer ----------------
// Tile: 128 nodes x 128 outs, K=256 (z = [agg | h]). 4 waves, each owns 32 outs.
// agg input is stripe-major aggs[4][NN][32].

template <bool SCORE>
__global__ __launch_bounds__(256) void linear_mfma(
    const unsigned short* __restrict__ aggs, const unsigned short* __restrict__ hb,
    const unsigned short* __restrict__ Wcat, const float* __restrict__ bl,
    unsigned short* __restrict__ hout,
    const float* __restrict__ Ws, const float* __restrict__ bsp,
    const float* __restrict__ alphap, const float* __restrict__ rr,
    const float* __restrict__ xw, float* __restrict__ out) {
  __shared__ unsigned short zl[128 * 256];  // 64 KiB; rows of 32 16B-chunks, chunk^=(row&7)
  __shared__ float sbuf[128];

  const int t = threadIdx.x;
  const int wid = t >> 6;
  const int l = t & 63;
  const int lg = l >> 4;   // k-group 0..3
  const int lm = l & 15;   // m (A) / n (B) within fragment
  const int node0 = blockIdx.x * 128;
  const int nb = wid * 32;

  // B fragments from global (L2-resident, 64KB reused by all blocks)
  short8v bfr[2][8];
  #pragma unroll
  for (int nf = 0; nf < 2; ++nf)
    #pragma unroll
    for (int kt = 0; kt < 8; ++kt)
      bfr[nf][kt] = *(const short8v*)(Wcat + (size_t)(nb + nf * 16 + lm) * 256 + kt * 32 + lg * 8);

  if (SCORE && t < 128) sbuf[t] = 0.f;

  // stage z = [agg | h] for 128 nodes, 16B/lane/iter, swizzled chunk placement
  #pragma unroll
  for (int q = 0; q < 16; ++q) {
    int idx = q * 256 + t;
    int row = idx >> 5;       // node-local 0..127
    int c = idx & 31;         // global k-chunk (16B = 8 bf16)
    int node = node0 + row; if (node >= NN) node = NN - 1;
    const unsigned short* src = (c < 16)
        ? (aggs + ((size_t)(c >> 2) * NN + node) * 32 + (c & 3) * 8)
        : (hb + (size_t)node * DD + (c - 16) * 8);
    short8v v = *(const short8v*)src;
    int cs = c ^ (row & 7);
    *(short8v*)(&zl[row * 256 + cs * 8]) = v;
  }
  __syncthreads();

  float4v acc[8][2];
  #pragma unroll
  for (int mf = 0; mf < 8; ++mf) {
    acc[mf][0] = (float4v){0.f, 0.f, 0.f, 0.f};
    acc[mf][1] = (float4v){0.f, 0.f, 0.f, 0.f};
  }

  #pragma unroll
  for (int kt = 0; kt < 8; ++kt) {
    short8v afr[8];
    #pragma unroll
    for (int mf = 0; mf < 8; ++mf) {
      int row = mf * 16 + lm;
      int c = (kt * 4 + lg) ^ (row & 7);
      afr[mf] = *(const short8v*)(&zl[row * 256 + c * 8]);
    }
    #pragma unroll
    for (int mf = 0; mf < 8; ++mf) {
      acc[mf][0] = __builtin_amdgcn_mfma_f32_16x16x32_bf16(afr[mf], bfr[0][kt], acc[mf][0], 0, 0, 0);
      acc[mf][1] = __builtin_amdgcn_mfma_f32_16x16x32_bf16(afr[mf], bfr[1][kt], acc[mf][1], 0, 0, 0);
    }
  }

  const float b0 = bl[nb + lm];
  const float b1 = bl[nb + 16 + lm];

  if (!SCORE) {
    #pragma unroll
    for (int mf = 0; mf < 8; ++mf) {
      #pragma unroll
      for (int r = 0; r < 4; ++r) {
        int row = node0 + mf * 16 + lg * 4 + r;
        if (row < NN) {
          hout[(size_t)row * DD + nb + lm]      = f2b(fmaxf(acc[mf][0][r] + b0, 0.f));
          hout[(size_t)row * DD + nb + 16 + lm] = f2b(fmaxf(acc[mf][1][r] + b1, 0.f));
        }
      }
    }
  } else {
    const float w0 = Ws[nb + lm];
    const float w1 = Ws[nb + 16 + lm];
    #pragma unroll
    for (int mf = 0; mf < 8; ++mf) {
      #pragma unroll
      for (int r = 0; r < 4; ++r) {
        float p = fmaxf(acc[mf][0][r] + b0, 0.f) * w0
                + fmaxf(acc[mf][1][r] + b1, 0.f) * w1;
        p += __shfl_xor(p, 1);
        p += __shfl_xor(p, 2);
        p += __shfl_xor(p, 4);
        p += __shfl_xor(p, 8);
        if (lm == 0) atomicAdd(&sbuf[mf * 16 + lg * 4 + r], p);
      }
    }
    __syncthreads();
    if (t < 128) {
      int node = node0 + t;
      if (node < NN) {
        float a = 1.f / (1.f + expf(-alphap[0]));
        float score = sbuf[t] + xw[node] + bsp[0];
        out[node] = a * rr[node] + (1.f - a) * score;
      }
    }
  }
}

// ---------------- launch ----------------

extern "C" void kernel_launch(void* const* d_in, const int* in_sizes, int n_in,
                              void* d_out, int out_size, void* d_ws, size_t ws_size,
                              hipStream_t stream) {
  const float* x   = (const float*)d_in[0];
  const int*   ei  = (const int*)d_in[1];
  const float* rr  = (const float*)d_in[2];
  const float* Wl1 = (const float*)d_in[3];
  const float* bl1 = (const float*)d_in[4];
  const float* Wr1 = (const float*)d_in[5];
  const float* Wl2 = (const float*)d_in[6];
  const float* bl2 = (const float*)d_in[7];
  const float* Wr2 = (const float*)d_in[8];
  const float* Wsc = (const float*)d_in[9];
  const float* bs  = (const float*)d_in[10];
  const float* al  = (const float*)d_in[11];
  const int* srcv = ei;
  const int* dstv = ei + NE;
  float* out = (float*)d_out;

  size_t off = 0;
  auto nxt = [&](size_t bytes) {
    size_t cur = off; off += (bytes + 255) & ~(size_t)255; return cur;
  };
  int*            ghist  = (int*)((char*)d_ws + nxt((size_t)B1 * NBUCK * 4));
  int*            goff   = (int*)((char*)d_ws + nxt((size_t)B1 * NBUCK * 4));
  int*            btot   = (int*)((char*)d_ws + nxt((size_t)NBUCK * 4));
  int*            qctr   = (int*)((char*)d_ws + nxt(16 * 4));
  int*            rowptr = (int*)((char*)d_ws + nxt((size_t)(NN + 1) * 4));
  int*            col    = (int*)((char*)d_ws + nxt((size_t)NE * 4));
  unsigned*       tmp    = (unsigned*)((char*)d_ws + nxt((size_t)NE * 4));
  unsigned short* xb     = (unsigned short*)((char*)d_ws + nxt((size_t)NN * DD * 2));
  unsigned short* aggs   = (unsigned short*)((char*)d_ws + nxt((size_t)NN * DD * 2));
  unsigned short* h1b    = (unsigned short*)((char*)d_ws + nxt((size_t)NN * DD * 2));
  unsigned short* W1     = (unsigned short*)((char*)d_ws + nxt((size_t)DD * 256 * 2));
  unsigned short* W2     = (unsigned short*)((char*)d_ws + nxt((size_t)DD * 256 * 2));
  float*          xw     = (float*)((char*)d_ws + nxt((size_t)NN * 4));

  hipMemsetAsync(qctr, 0, 16 * 4, stream);
  k_prep<<<B1 + CONVB + PREPB, 256, 0, stream>>>(
      dstv, ghist, x, Wsc, xb, xw, Wl1, Wr1, Wl2, Wr2, W1, W2);
  scan_cols<<<NBUCK, 256, 0, stream>>>(ghist, goff, btot);
  scatter1<<<B1, 256, 0, stream>>>(srcv, dstv, goff, btot, tmp);
  bucketsort<<<NBUCK, 256, 0, stream>>>(tmp, btot, rowptr, col);

  // layer 1
  agg_queue<<<AGGBLK, 256, 0, stream>>>(xb, rowptr, col, qctr, aggs);
  linear_mfma<false><<<(NN + 127) / 128, 256, 0, stream>>>(
      aggs, xb, W1, bl1, h1b, nullptr, nullptr, nullptr, nullptr, nullptr, nullptr);
  // layer 2 (+ residual + score head + blend, fused)
  agg_queue<<<AGGBLK, 256, 0, stream>>>(h1b, rowptr, col, qctr + 8, aggs);
  linear_mfma<true><<<(NN + 127) / 128, 256, 0, stream>>>(
      aggs, h1b, W2, bl2, nullptr, Wsc, bs, al, rr, xw, out);
}

// Round 10
// 120.334 us; speedup vs baseline: 4.7555x; 4.7555x over previous
//
#include <hip/hip_runtime.h>

#define NN 50000
#define NE 800000
#define DD 128

#define NBUCK 196   // ceil(NN/256), bucket = dst >> 8
#define EPB   2048  // edges per block in pass 1
#define B1    391   // ceil(NE/EPB)
#define CAP   5120  // max edges per bucket (mean 4082, std 64 -> +16 sigma)
#define CONVB 12500 // NN/4 conv blocks
#define PREPB 128   // 2*128*256/512

typedef __attribute__((ext_vector_type(8))) short short8v;
typedef __attribute__((ext_vector_type(4))) float float4v;

static __device__ __forceinline__ unsigned short f2b(float f) {
  union { float f; unsigned u; } v; v.f = f;
  unsigned r = v.u + 0x7fff + ((v.u >> 16) & 1);
  return (unsigned short)(r >> 16);
}
static __device__ __forceinline__ float b2f(unsigned short b) {
  union { unsigned u; float f; } v; v.u = ((unsigned)b) << 16;
  return v.f;
}

// exclusive scan over 256 threads (trailing barrier makes ws reusable)
static __device__ __forceinline__ int excl_scan256(int v, int* ws) {
  int t = threadIdx.x, lane = t & 63, w = t >> 6;
  int s = v;
  #pragma unroll
  for (int off = 1; off < 64; off <<= 1) {
    int u = __shfl_up(s, off);
    if (lane >= off) s += u;
  }
  if (lane == 63) ws[w] = s;
  __syncthreads();
  int add = 0;
  #pragma unroll
  for (int k = 0; k < 3; ++k)
    if (k < w) add += ws[k];
  __syncthreads();
  return add + s - v;
}

// ---- k_prep: role-split {histogram | x->bf16+fp8 + x.Ws | weight pack} ----

__global__ __launch_bounds__(256) void k_prep(
    const int* __restrict__ dst, int* __restrict__ ghist,
    const float* __restrict__ x, const float* __restrict__ Wsc,
    unsigned short* __restrict__ xb, unsigned char* __restrict__ xf8,
    float* __restrict__ xw,
    const float* __restrict__ Wl1, const float* __restrict__ Wr1,
    const float* __restrict__ Wl2, const float* __restrict__ Wr2,
    unsigned short* __restrict__ W1, unsigned short* __restrict__ W2) {
  __shared__ int hs[NBUCK];
  const int b = blockIdx.x;
  const int t = threadIdx.x;
  if (b < B1) {
    for (int i = t; i < NBUCK; i += 256) hs[i] = 0;
    __syncthreads();
    int base = b * EPB;
    for (int i = t; i < EPB; i += 256) {
      int e = base + i;
      if (e < NE) atomicAdd(&hs[dst[e] >> 8], 1);
    }
    __syncthreads();
    for (int i = t; i < NBUCK; i += 256) ghist[b * NBUCK + i] = hs[i];
  } else if (b < B1 + CONVB) {
    int node = (b - B1) * 4 + (t >> 6);
    int lane = t & 63;
    float2 v = *(const float2*)(x + (size_t)node * DD + lane * 2);
    ushort2 o; o.x = f2b(v.x); o.y = f2b(v.y);
    *(ushort2*)(xb + (size_t)node * DD + lane * 2) = o;
    int p8 = __builtin_amdgcn_cvt_pk_fp8_f32(v.x, v.y, 0, false);
    *(unsigned short*)(xf8 + (size_t)node * DD + lane * 2) = (unsigned short)p8;
    float p = v.x * Wsc[lane * 2] + v.y * Wsc[lane * 2 + 1];
    #pragma unroll
    for (int m = 1; m < 64; m <<= 1) p += __shfl_xor(p, m);
    if (lane == 0) xw[node] = p;
  } else {
    int idx0 = ((b - B1 - CONVB) * 256 + t) * 2;
    #pragma unroll
    for (int u = 0; u < 2; ++u) {
      int idx = idx0 + u;
      int half = idx >> 15;
      int i = idx & 32767;
      int o = i >> 8;
      int k = i & 255;
      const float* Wl = half ? Wl2 : Wl1;
      const float* Wr = half ? Wr2 : Wr1;
      float v = (k < DD) ? Wl[o * DD + k] : Wr[o * DD + (k - DD)];
      (half ? W2 : W1)[i] = f2b(v);
    }
  }
}

// ---- scan_cols: one block per bucket, scan 391 per-block counts ----

__global__ __launch_bounds__(256) void scan_cols(const int* __restrict__ ghist,
                                                 int* __restrict__ goff,
                                                 int* __restrict__ btot) {
  __shared__ int ws[4];
  const int j = blockIdx.x, t = threadIdx.x;
  int b0 = 2 * t, b1 = 2 * t + 1;
  int v0 = (b0 < B1) ? ghist[b0 * NBUCK + j] : 0;
  int v1 = (b1 < B1) ? ghist[b1 * NBUCK + j] : 0;
  int excl = excl_scan256(v0 + v1, ws);
  if (b0 < B1) goff[b0 * NBUCK + j] = excl;
  if (b1 < B1) goff[b1 * NBUCK + j] = excl + v0;
  if (t == 255) btot[j] = excl + v0 + v1;
}

// ---- scatter1: in-block binstart scan + bucket scatter ----

__global__ __launch_bounds__(256) void scatter1(const int* __restrict__ src,
                                                const int* __restrict__ dst,
                                                const int* __restrict__ goff,
                                                const int* __restrict__ btot,
                                                unsigned* __restrict__ tmp) {
  __shared__ int cur[NBUCK];
  __shared__ int ws[4];
  const int t = threadIdx.x;
  int vb = (t < NBUCK) ? btot[t] : 0;
  int exb = excl_scan256(vb, ws);
  if (t < NBUCK) cur[t] = exb + goff[blockIdx.x * NBUCK + t];
  __syncthreads();
  int base = blockIdx.x * EPB;
  for (int i = t; i < EPB; i += 256) {
    int e = base + i;
    if (e < NE) {
      int d = dst[e];
      int pos = atomicAdd(&cur[d >> 8], 1);
      tmp[pos] = ((unsigned)(d & 255) << 20) | (unsigned)src[e];
    }
  }
}

// ---- bucketsort: one block per bucket, LDS counting sort -> rowptr/col ----

__global__ __launch_bounds__(256) void bucketsort(const unsigned* __restrict__ tmp,
                                                  const int* __restrict__ btot,
                                                  int* __restrict__ rowptr,
                                                  int* __restrict__ col) {
  __shared__ unsigned vals[CAP];
  __shared__ int cnt[256];
  __shared__ int ws[4];
  __shared__ int s0_sh;
  const int b = blockIdx.x, j = threadIdx.x;
  int vb = (j < NBUCK) ? btot[j] : 0;
  int exb = excl_scan256(vb, ws);
  if (j == b) s0_sh = exb;
  cnt[j] = 0;
  __syncthreads();
  const int s0 = s0_sh;
  int n = btot[b];
  if (n > CAP) n = CAP;
  for (int i = j; i < n; i += 256) {
    unsigned v = tmp[s0 + i];
    vals[i] = v;
    atomicAdd(&cnt[v >> 20], 1);
  }
  __syncthreads();
  int c = cnt[j];
  int excl = excl_scan256(c, ws);
  int node = b * 256 + j;
  if (node < NN) rowptr[node] = s0 + excl;
  if (b == 0 && j == 0) rowptr[NN] = NE;
  cnt[j] = excl;  // reuse as cursor (scan helper ended with a barrier)
  __syncthreads();
  for (int i = j; i < n; i += 256) {
    unsigned v = vals[i];
    int pos = atomicAdd(&cnt[v >> 20], 1);
    col[s0 + pos] = (int)(v & 0xFFFFF);
  }
}

// ---- agg_fp8: mean aggregation gathering fp8 rows (128B/row) ----
// 8 lanes/node, each lane owns 16 dims: one 16B load per edge, HW fp8 decode,
// fp32 accumulate, bf16 output row for the MFMA stage.

__global__ __launch_bounds__(256) void agg_fp8(const unsigned char* __restrict__ hf8,
                                               const int* __restrict__ rowptr,
                                               const int* __restrict__ col,
                                               unsigned short* __restrict__ agg) {
  int node = (blockIdx.x * 256 + threadIdx.x) >> 3;
  if (node >= NN) return;
  const int q = threadIdx.x & 7;
  const unsigned char* hb = hf8 + q * 16;
  int beg = rowptr[node], end = rowptr[node + 1];
  float acc[16];
  #pragma unroll
  for (int k = 0; k < 16; ++k) acc[k] = 0.f;
  int e = beg;
  for (; e + 8 <= end; e += 8) {
    uint4 v[8];
    #pragma unroll
    for (int j = 0; j < 8; ++j)
      v[j] = *(const uint4*)(hb + (size_t)col[e + j] * DD);
    #pragma unroll
    for (int j = 0; j < 8; ++j) {
      #pragma unroll
      for (int d = 0; d < 4; ++d) {
        unsigned w = (&v[j].x)[d];
        auto lo = __builtin_amdgcn_cvt_pk_f32_fp8(w, false);
        auto hi = __builtin_amdgcn_cvt_pk_f32_fp8(w, true);
        acc[d * 4 + 0] += lo[0];
        acc[d * 4 + 1] += lo[1];
        acc[d * 4 + 2] += hi[0];
        acc[d * 4 + 3] += hi[1];
      }
    }
  }
  for (; e < end; ++e) {
    uint4 v = *(const uint4*)(hb + (size_t)col[e] * DD);
    #pragma unroll
    for (int d = 0; d < 4; ++d) {
      unsigned w = (&v.x)[d];
      auto lo = __builtin_amdgcn_cvt_pk_f32_fp8(w, false);
      auto hi = __builtin_amdgcn_cvt_pk_f32_fp8(w, true);
      acc[d * 4 + 0] += lo[0];
      acc[d * 4 + 1] += lo[1];
      acc[d * 4 + 2] += hi[0];
      acc[d * 4 + 3] += hi[1];
    }
  }
  float inv = 1.0f / fmaxf((float)(end - beg), 1.0f);
  short8v o0, o1;
  #pragma unroll
  for (int k = 0; k < 8; ++k) {
    o0[k] = (short)f2b(acc[k] * inv);
    o1[k] = (short)f2b(acc[8 + k] * inv);
  }
  *(short8v*)(agg + (size_t)node * DD + q * 16) = o0;
  *(short8v*)(agg + (size_t)node * DD + q * 16 + 8) = o1;
}

// ---------------- fused MFMA linear layer ----------------
// Tile: 128 nodes x 128 outs, K=256 (z = [agg | h]). 4 waves, each owns 32 outs.
// <false> epilogue also emits the fp8 copy of h1 for the layer-2 gather.

template <bool SCORE>
__global__ __launch_bounds__(256) void linear_mfma(
    const unsigned short* __restrict__ aggb, const unsigned short* __restrict__ hb,
    const unsigned short* __restrict__ Wcat, const float* __restrict__ bl,
    unsigned short* __restrict__ hout, unsigned char* __restrict__ hf8out,
    const float* __restrict__ Ws, const float* __restrict__ bsp,
    const float* __restrict__ alphap, const float* __restrict__ rr,
    const float* __restrict__ xw, float* __restrict__ out) {
  __shared__ unsigned short zl[128 * 256];  // 64 KiB; rows of 32 16B-chunks, chunk^=(row&7)
  __shared__ float sbuf[128];

  const int t = threadIdx.x;
  const int wid = t >> 6;
  const int l = t & 63;
  const int lg = l >> 4;   // k-group 0..3
  const int lm = l & 15;   // m (A) / n (B) within fragment
  const int node0 = blockIdx.x * 128;
  const int nb = wid * 32;

  // B fragments from global (L2-resident, 64KB reused by all blocks)
  short8v bfr[2][8];
  #pragma unroll
  for (int nf = 0; nf < 2; ++nf)
    #pragma unroll
    for (int kt = 0; kt < 8; ++kt)
      bfr[nf][kt] = *(const short8v*)(Wcat + (size_t)(nb + nf * 16 + lm) * 256 + kt * 32 + lg * 8);

  if (SCORE && t < 128) sbuf[t] = 0.f;

  // stage z = [agg | h] for 128 nodes, 16B/lane/iter, swizzled chunk placement
  #pragma unroll
  for (int q = 0; q < 16; ++q) {
    int idx = q * 256 + t;
    int row = idx >> 5;       // node-local 0..127
    int c = idx & 31;         // global k-chunk (16B = 8 bf16)
    int node = node0 + row; if (node >= NN) node = NN - 1;
    const unsigned short* src = (c < 16)
        ? (aggb + (size_t)node * DD + c * 8)
        : (hb   + (size_t)node * DD + (c - 16) * 8);
    short8v v = *(const short8v*)src;
    int cs = c ^ (row & 7);
    *(short8v*)(&zl[row * 256 + cs * 8]) = v;
  }
  __syncthreads();

  float4v acc[8][2];
  #pragma unroll
  for (int mf = 0; mf < 8; ++mf) {
    acc[mf][0] = (float4v){0.f, 0.f, 0.f, 0.f};
    acc[mf][1] = (float4v){0.f, 0.f, 0.f, 0.f};
  }

  #pragma unroll
  for (int kt = 0; kt < 8; ++kt) {
    short8v afr[8];
    #pragma unroll
    for (int mf = 0; mf < 8; ++mf) {
      int row = mf * 16 + lm;
      int c = (kt * 4 + lg) ^ (row & 7);
      afr[mf] = *(const short8v*)(&zl[row * 256 + c * 8]);
    }
    #pragma unroll
    for (int mf = 0; mf < 8; ++mf) {
      acc[mf][0] = __builtin_amdgcn_mfma_f32_16x16x32_bf16(afr[mf], bfr[0][kt], acc[mf][0], 0, 0, 0);
      acc[mf][1] = __builtin_amdgcn_mfma_f32_16x16x32_bf16(afr[mf], bfr[1][kt], acc[mf][1], 0, 0, 0);
    }
  }

  const float b0 = bl[nb + lm];
  const float b1 = bl[nb + 16 + lm];

  if (!SCORE) {
    #pragma unroll
    for (int mf = 0; mf < 8; ++mf) {
      #pragma unroll
      for (int r = 0; r < 4; ++r) {
        int row = node0 + mf * 16 + lg * 4 + r;
        if (row < NN) {
          float f0 = fmaxf(acc[mf][0][r] + b0, 0.f);
          float f1 = fmaxf(acc[mf][1][r] + b1, 0.f);
          hout[(size_t)row * DD + nb + lm]      = f2b(f0);
          hout[(size_t)row * DD + nb + 16 + lm] = f2b(f1);
          int p0 = __builtin_amdgcn_cvt_pk_fp8_f32(f0, 0.f, 0, false);
          int p1 = __builtin_amdgcn_cvt_pk_fp8_f32(f1, 0.f, 0, false);
          hf8out[(size_t)row * DD + nb + lm]      = (unsigned char)p0;
          hf8out[(size_t)row * DD + nb + 16 + lm] = (unsigned char)p1;
        }
      }
    }
  } else {
    const float w0 = Ws[nb + lm];
    const float w1 = Ws[nb + 16 + lm];
    #pragma unroll
    for (int mf = 0; mf < 8; ++mf) {
      #pragma unroll
      for (int r = 0; r < 4; ++r) {
        float p = fmaxf(acc[mf][0][r] + b0, 0.f) * w0
                + fmaxf(acc[mf][1][r] + b1, 0.f) * w1;
        p += __shfl_xor(p, 1);
        p += __shfl_xor(p, 2);
        p += __shfl_xor(p, 4);
        p += __shfl_xor(p, 8);
        if (lm == 0) atomicAdd(&sbuf[mf * 16 + lg * 4 + r], p);
      }
    }
    __syncthreads();
    if (t < 128) {
      int node = node0 + t;
      if (node < NN) {
        float a = 1.f / (1.f + expf(-alphap[0]));
        float score = sbuf[t] + xw[node] + bsp[0];
        out[node] = a * rr[node] + (1.f - a) * score;
      }
    }
  }
}

// ---------------- launch ----------------

extern "C" void kernel_launch(void* const* d_in, const int* in_sizes, int n_in,
                              void* d_out, int out_size, void* d_ws, size_t ws_size,
                              hipStream_t stream) {
  const float* x   = (const float*)d_in[0];
  const int*   ei  = (const int*)d_in[1];
  const float* rr  = (const float*)d_in[2];
  const float* Wl1 = (const float*)d_in[3];
  const float* bl1 = (const float*)d_in[4];
  const float* Wr1 = (const float*)d_in[5];
  const float* Wl2 = (const float*)d_in[6];
  const float* bl2 = (const float*)d_in[7];
  const float* Wr2 = (const float*)d_in[8];
  const float* Wsc = (const float*)d_in[9];
  const float* bs  = (const float*)d_in[10];
  const float* al  = (const float*)d_in[11];
  const int* srcv = ei;
  const int* dstv = ei + NE;
  float* out = (float*)d_out;

  size_t off = 0;
  auto nxt = [&](size_t bytes) {
    size_t cur = off; off += (bytes + 255) & ~(size_t)255; return cur;
  };
  int*            ghist  = (int*)((char*)d_ws + nxt((size_t)B1 * NBUCK * 4));
  int*            goff   = (int*)((char*)d_ws + nxt((size_t)B1 * NBUCK * 4));
  int*            btot   = (int*)((char*)d_ws + nxt((size_t)NBUCK * 4));
  int*            rowptr = (int*)((char*)d_ws + nxt((size_t)(NN + 1) * 4));
  int*            col    = (int*)((char*)d_ws + nxt((size_t)NE * 4));
  unsigned*       tmp    = (unsigned*)((char*)d_ws + nxt((size_t)NE * 4));
  unsigned short* xb     = (unsigned short*)((char*)d_ws + nxt((size_t)NN * DD * 2));
  unsigned short* aggb   = (unsigned short*)((char*)d_ws + nxt((size_t)NN * DD * 2));
  unsigned short* h1b    = (unsigned short*)((char*)d_ws + nxt((size_t)NN * DD * 2));
  unsigned char*  xf8    = (unsigned char*)((char*)d_ws + nxt((size_t)NN * DD));
  unsigned char*  h1f8   = (unsigned char*)((char*)d_ws + nxt((size_t)NN * DD));
  unsigned short* W1     = (unsigned short*)((char*)d_ws + nxt((size_t)DD * 256 * 2));
  unsigned short* W2     = (unsigned short*)((char*)d_ws + nxt((size_t)DD * 256 * 2));
  float*          xw     = (float*)((char*)d_ws + nxt((size_t)NN * 4));

  k_prep<<<B1 + CONVB + PREPB, 256, 0, stream>>>(
      dstv, ghist, x, Wsc, xb, xf8, xw, Wl1, Wr1, Wl2, Wr2, W1, W2);
  scan_cols<<<NBUCK, 256, 0, stream>>>(ghist, goff, btot);
  scatter1<<<B1, 256, 0, stream>>>(srcv, dstv, goff, btot, tmp);
  bucketsort<<<NBUCK, 256, 0, stream>>>(tmp, btot, rowptr, col);

  // layer 1
  agg_fp8<<<(NN * 8 + 255) / 256, 256, 0, stream>>>(xf8, rowptr, col, aggb);
  linear_mfma<false><<<(NN + 127) / 128, 256, 0, stream>>>(
      aggb, xb, W1, bl1, h1b, h1f8, nullptr, nullptr, nullptr, nullptr, nullptr, nullptr);
  // layer 2 (+ residual + score head + blend, fused)
  agg_fp8<<<(NN * 8 + 255) / 256, 256, 0, stream>>>(h1f8, rowptr, col, aggb);
  linear_mfma<true><<<(NN + 127) / 128, 256, 0, stream>>>(
      aggb, h1b, W2, bl2, nullptr, nullptr, Wsc, bs, al, rr, xw, out);
}